// Round 7
// baseline (97.654 us; speedup 1.0000x reference)
//
#include <hip/hip_runtime.h>

// QLinear: y[n,o] = round((sum_k (x[n,k]-xz)*(w[o,k]-wz) + bias[o]) * M + yz)
// N=65536, K=512, OUT=512.
// Exact i8 path: (x-128),(w-128) in [-128,127]; |dot+bias| < 2^24; f32 epilogue exact.
// R7: 128x128 tile, A+B reg-staged (distance 2) -> fragment-major LDS (conflict-free
//     by construction), lgkm-only barriers so global prefetch is never drained.

#define K_DIM 512
#define OUTF  512
#define NT    8            // K_DIM / 64

typedef __attribute__((ext_vector_type(4))) int   i32x4;
typedef __attribute__((ext_vector_type(4))) float f32x4;

// ---------- prepass: weight int32 -> i8 (w - wz), row-major [o][k] ----------
__global__ void wprep(const int* __restrict__ W, unsigned int* __restrict__ Wb,
                      const float* __restrict__ wzp) {
    const int wz = __float2int_rn(wzp[0]);
    int idx = (blockIdx.x * blockDim.x + threadIdx.x) * 4;
    i32x4 w = *reinterpret_cast<const i32x4*>(W + idx);
    unsigned int p = ((unsigned int)(w[0] - wz) & 0xffu)
                   | (((unsigned int)(w[1] - wz) & 0xffu) << 8)
                   | (((unsigned int)(w[2] - wz) & 0xffu) << 16)
                   | (((unsigned int)(w[3] - wz) & 0xffu) << 24);
    Wb[idx >> 2] = p;
}

__global__ __launch_bounds__(512, 4)
void qgemm(const float* __restrict__ X,
           const unsigned char* __restrict__ Wb,
           const int* __restrict__ bias,
           const float* __restrict__ Mp,
           const float* __restrict__ xzp,
           const float* __restrict__ yzp,
           float* __restrict__ Y) {
    // Fragment-major LDS: per buffer, A = 8 frags x 64 lanes x 16B (8KB), B same.
    // Thread tid owns byte range [tid*16, tid*16+16) of A and of B -> zero-conflict
    // writes; wave frag reads are lane-contiguous 1024B -> zero-conflict reads.
    __shared__ unsigned char lds[2][16384];

    const int tid  = threadIdx.x;
    const int lane = tid & 63;
    const int wid  = tid >> 6;                 // 0..7
    const int wr   = wid >> 2;                 // row 64-strip
    const int wc   = wid & 3;                  // col 32-strip
    const int fr   = lane & 15;
    const int fq   = lane >> 4;

    // XCD-contiguous bijective swizzle (2048 = 8 * 256); col-tile fastest so the
    // 4 col-blocks sharing an x row-panel co-reside on one XCD's L2.
    const int b = blockIdx.x;
    const int lid = (b & 7) * 256 + (b >> 3);
    const int row0 = (lid >> 2) * 128;
    const int n0   = (lid & 3) * 128;

    const float xzf = xzp[0];

    // staging map (fragment-major): thread -> tile-row (tid>>6)*16 + (tid&15),
    // k-slot ((tid>>4)&3)*16 bytes. A source is f32 (16 floats), B is i8 (16 B).
    const int trow = ((tid >> 6) << 4) + (tid & 15);
    const int tk   = ((tid >> 4) & 3) * 16;
    const float* xbase = X + (size_t)(row0 + trow) * K_DIM + tk;
    const unsigned char* wbase = Wb + (size_t)(n0 + trow) * K_DIM + tk;
    const int dA = tid * 16;            // LDS byte offsets
    const int dB = 8192 + tid * 16;

    f32x4 ra[2][4];                     // two staging sets (prefetch distance 2)
    i32x4 rb[2];

    auto stage = [&](int t) {
        const int s = t & 1;
        const float* xp = xbase + t * 64;
        #pragma unroll
        for (int q = 0; q < 4; ++q)
            ra[s][q] = *reinterpret_cast<const f32x4*>(xp + q * 4);
        rb[s] = *reinterpret_cast<const i32x4*>(wbase + t * 64);
    };
    auto convwrite = [&](int t) {
        const int s = t & 1;
        i32x4 pa;
        #pragma unroll
        for (int q = 0; q < 4; ++q) {
            unsigned int u0 = (unsigned int)((int)(ra[s][q][0] - xzf)) & 0xffu;
            unsigned int u1 = (unsigned int)((int)(ra[s][q][1] - xzf)) & 0xffu;
            unsigned int u2 = (unsigned int)((int)(ra[s][q][2] - xzf)) & 0xffu;
            unsigned int u3 = (unsigned int)((int)(ra[s][q][3] - xzf)) & 0xffu;
            pa[q] = (int)(u0 | (u1 << 8) | (u2 << 16) | (u3 << 24));
        }
        *reinterpret_cast<i32x4*>(&lds[s][dA]) = pa;
        *reinterpret_cast<i32x4*>(&lds[s][dB]) = rb[s];
    };

    // bias folded into accumulator init
    const int c0 = n0 + wc * 32;
    const int bv0 = bias[c0 + fr];
    const int bv1 = bias[c0 + 16 + fr];
    i32x4 acc[4][2];
    #pragma unroll
    for (int m = 0; m < 4; ++m) {
        acc[m][0] = i32x4{bv0, bv0, bv0, bv0};
        acc[m][1] = i32x4{bv1, bv1, bv1, bv1};
    }

    auto compute = [&](int t) {
        const int s = t & 1;
        i32x4 af[4], bf[2];
        #pragma unroll
        for (int m = 0; m < 4; ++m)
            af[m] = *reinterpret_cast<const i32x4*>(&lds[s][(wr * 4 + m) * 1024 + lane * 16]);
        #pragma unroll
        for (int n = 0; n < 2; ++n)
            bf[n] = *reinterpret_cast<const i32x4*>(&lds[s][8192 + (wc * 2 + n) * 1024 + lane * 16]);
        #pragma unroll
        for (int m = 0; m < 4; ++m)
            #pragma unroll
            for (int n = 0; n < 2; ++n)
                acc[m][n] = __builtin_amdgcn_mfma_i32_16x16x64_i8(
                    af[m], bf[n], acc[m][n], 0, 0, 0);
    };

    auto barrier = [&]() {
        // drain only LDS ops -- global prefetch loads stay in flight across it
        asm volatile("s_waitcnt lgkmcnt(0)" ::: "memory");
        __builtin_amdgcn_s_barrier();
    };

    // prologue: t=0,1 loads in flight; write t=0 (register deps wait only t=0's loads)
    stage(0);
    stage(1);
    convwrite(0);
    barrier();

    #pragma unroll
    for (int t = 0; t < NT; ++t) {
        if (t + 2 < NT) stage(t + 2);        // far-ahead issue first
        compute(t);
        if (t + 1 < NT) convwrite(t + 1);    // consume loads one full iteration old
        barrier();
    }

    // epilogue: y = rintf(acc * M + yz)  (bias pre-folded)
    const float Mv = Mp[0], yz = yzp[0];
    #pragma unroll
    for (int n = 0; n < 2; ++n) {
        const int col = c0 + n * 16 + fr;
        #pragma unroll
        for (int m = 0; m < 4; ++m) {
            const int row = row0 + wr * 64 + m * 16 + fq * 4;
            float* yp = Y + (size_t)row * OUTF + col;
            #pragma unroll
            for (int j = 0; j < 4; ++j)
                yp[(size_t)j * OUTF] = rintf((float)acc[m][n][j] * Mv + yz);
        }
    }
}

extern "C" void kernel_launch(void* const* d_in, const int* in_sizes, int n_in,
                              void* d_out, int out_size, void* d_ws, size_t ws_size,
                              hipStream_t stream) {
    const float* x    = (const float*)d_in[0];
    const int*   w    = (const int*)d_in[1];
    const int*   bias = (const int*)d_in[2];
    const float* M    = (const float*)d_in[3];
    const float* xz   = (const float*)d_in[4];
    const float* wz   = (const float*)d_in[5];
    const float* yz   = (const float*)d_in[6];
    float* y = (float*)d_out;

    unsigned int* Wb = (unsigned int*)d_ws;     // 512*512 i8 = 256 KB

    wprep<<<256, 256, 0, stream>>>(w, Wb, wz);
    qgemm<<<2048, 512, 0, stream>>>(x, (const unsigned char*)Wb, bias, M, xz, yz, y);
}